// Round 6
// baseline (371.830 us; speedup 1.0000x reference)
//
#include <hip/hip_runtime.h>
#include <hip/hip_bf16.h>

// Connected filter:
//   vals[i] = sigmoid(clamp(100*(attrs[i]·w + b), ±12)) * residue[i]
//   cum[i]  = sum of vals along parent chain from i up to root (dummy N terminates)
//   out[p]  = cum[pixel_to_node[p]]
// parent[i] < i (topological), parent[N] = N (dummy, val 0).
//
// Pipeline:
//   1. gate+pack, 2. leveled walk (cutoffs 16K/256K/1M/N) -> cum
//   3. BINNED pixel gather: bin nodes into 8 slices of 2MB (per-XCD-L2-sized),
//      deterministic scan-based compaction (ballot/popc, no atomics),
//      gather per-bin (L2-resident), merge back in pixel order.
// Lessons baked in:
//  - nt-* builtins need ext_vector_type. nt-STORES double WRITE_SIZE -> never.
//  - ×8-contiguous-per-thread stores leak partial-line writebacks (95 vs 65MB)
//    -> one v4f store per iter, lane-dense (R1 pattern) in k_merge.

typedef float v2f __attribute__((ext_vector_type(2)));
typedef float v4f __attribute__((ext_vector_type(4)));
typedef int   v4i __attribute__((ext_vector_type(4)));

// ---------------- Kernel 1: gate + pack (par, val) into 8B records ------------
__global__ void k_gate_pack(const float* __restrict__ attrs,
                            const float* __restrict__ w,
                            const float* __restrict__ bias,
                            const float* __restrict__ residue,
                            const int*   __restrict__ parent,
                            int2* __restrict__ packed, int N) {
    int i = blockIdx.x * blockDim.x + threadIdx.x;
    if (i > N) return;
    if (i == N) { int2 p; p.x = N; p.y = __float_as_int(0.0f); packed[N] = p; return; }
    const v2f* a2 = reinterpret_cast<const v2f*>(attrs + (size_t)i * 6);
    v2f a0  = __builtin_nontemporal_load(a2 + 0);
    v2f a1  = __builtin_nontemporal_load(a2 + 1);
    v2f a2v = __builtin_nontemporal_load(a2 + 2);
    float logit = bias[0]
                + a0.x  * w[0] + a0.y  * w[1]
                + a1.x  * w[2] + a1.y  * w[3]
                + a2v.x * w[4] + a2v.y * w[5];
    float s = fminf(fmaxf(100.0f * logit, -12.0f), 12.0f);
    float gate = 1.0f / (1.0f + __expf(-s));
    float v = gate * __builtin_nontemporal_load(residue + i);
    int2 p; p.x = __builtin_nontemporal_load(parent + i); p.y = __float_as_int(v);
    packed[i] = p;
}

// ---------------- Kernel 2: leveled walk --------------------------------------
__global__ void k_walk_lvl0(const int2* __restrict__ packed,
                            float* __restrict__ cum, int hi, int N) {
    int i = blockIdx.x * blockDim.x + threadIdx.x;
    if (i >= hi) return;
    float s = 0.0f; int j = i;
    while (j != N) { int2 pv = packed[j]; s += __int_as_float(pv.y); j = pv.x; }
    cum[i] = s;
}

__global__ void k_walk_lvl(const int2* __restrict__ packed,
                           float* __restrict__ cum, int lo, int hi, int cutoff) {
    int i = lo + blockIdx.x * blockDim.x + threadIdx.x;
    if (i >= hi) return;
    float s = 0.0f; int j = i;
    do { int2 pv = packed[j]; s += __int_as_float(pv.y); j = pv.x; } while (j >= cutoff);
    cum[i] = s + cum[j];
}

// ---------------- Fallback: direct pixel gather (R5) --------------------------
__global__ void k_pixel_gather(const float* __restrict__ cum,
                               const int* __restrict__ ptn,
                               float* __restrict__ out, int M) {
    int t = blockIdx.x * blockDim.x + threadIdx.x;
    int base = t * 4;
    if (base + 3 < M) {
        v4i idx = __builtin_nontemporal_load(reinterpret_cast<const v4i*>(ptn) + t);
        float4 o;
        o.x = cum[idx.x]; o.y = cum[idx.y]; o.z = cum[idx.z]; o.w = cum[idx.w];
        reinterpret_cast<float4*>(out)[t] = o;
    } else {
        for (int p = base; p < M; ++p) out[p] = cum[ptn[p]];
    }
}

// ---------------- Binned gather pipeline ---------------------------------------
// Chunking: one wave handles 4096 pixels = 16 iters x 64 lanes x v4i.

__global__ void k_count(const int* __restrict__ ptn, int* __restrict__ counts,
                        int shift) {
    int wave = blockIdx.x * (blockDim.x >> 6) + (threadIdx.x >> 6);
    int lane = threadIdx.x & 63;
    const v4i* p4 = reinterpret_cast<const v4i*>(ptn) + (size_t)wave * 1024;
    int c0=0,c1=0,c2=0,c3=0,c4=0,c5=0,c6=0,c7=0;
    for (int t = 0; t < 16; ++t) {
        v4i ia = __builtin_nontemporal_load(p4 + t*64 + lane);
        #pragma unroll
        for (int c = 0; c < 4; ++c) {
            int bin = ia[c] >> shift;
            #define CNTB(B, C) { unsigned long long m = __ballot(bin == B); C += (int)__popcll(m); }
            CNTB(0,c0) CNTB(1,c1) CNTB(2,c2) CNTB(3,c3)
            CNTB(4,c4) CNTB(5,c5) CNTB(6,c6) CNTB(7,c7)
            #undef CNTB
        }
    }
    int v = 0;
    if      (lane == 0) v = c0; else if (lane == 1) v = c1;
    else if (lane == 2) v = c2; else if (lane == 3) v = c3;
    else if (lane == 4) v = c4; else if (lane == 5) v = c5;
    else if (lane == 6) v = c6; else if (lane == 7) v = c7;
    if (lane < 8) counts[wave*8 + lane] = v;
}

// 1 block, 512 threads = 8 bins x 64 lanes. Deterministic scan.
__global__ void k_scan(const int* __restrict__ counts, int* __restrict__ bases,
                       int* __restrict__ binStart, int nWaves) {
    int b = threadIdx.x >> 6;
    int lane = threadIdx.x & 63;
    int g = nWaves >> 6;
    int w0 = lane * g;
    int sum = 0;
    for (int w = w0; w < w0 + g; ++w) sum += counts[w*8 + b];
    int inc = sum;
    #pragma unroll
    for (int d = 1; d < 64; d <<= 1) {
        int o = __shfl_up(inc, d);
        if (lane >= d) inc += o;
    }
    int excl = inc - sum;
    __shared__ int totals[8];
    __shared__ int bstart[9];
    if (lane == 63) totals[b] = inc;
    __syncthreads();
    if (threadIdx.x == 0) {
        bstart[0] = 0;
        for (int i = 0; i < 8; ++i) bstart[i+1] = bstart[i] + totals[i];
        for (int i = 0; i < 9; ++i) binStart[i] = bstart[i];
    }
    __syncthreads();
    int run = bstart[b] + excl;
    for (int w = w0; w < w0 + g; ++w) { bases[w*8 + b] = run; run += counts[w*8 + b]; }
}

__global__ void k_scatter(const int* __restrict__ ptn, const int* __restrict__ bases,
                          int* __restrict__ nodes_b, int shift) {
    int wave = blockIdx.x * (blockDim.x >> 6) + (threadIdx.x >> 6);
    int lane = threadIdx.x & 63;
    unsigned long long lt = (1ull << lane) - 1ull;
    const v4i* p4 = reinterpret_cast<const v4i*>(ptn) + (size_t)wave * 1024;
    int mybase = (lane < 8) ? bases[wave*8 + lane] : 0;
    int w0=0,w1=0,w2=0,w3=0,w4=0,w5=0,w6=0,w7=0;
    for (int t = 0; t < 16; ++t) {
        v4i ia = __builtin_nontemporal_load(p4 + t*64 + lane);
        #pragma unroll
        for (int c = 0; c < 4; ++c) {
            int node = ia[c];
            int bin = node >> shift;
            int off = 0;
            #define STEPB(B, W) { unsigned long long m = __ballot(bin == B); \
                if (bin == B) off = W + (int)__popcll(m & lt); W += (int)__popcll(m); }
            STEPB(0,w0) STEPB(1,w1) STEPB(2,w2) STEPB(3,w3)
            STEPB(4,w4) STEPB(5,w5) STEPB(6,w6) STEPB(7,w7)
            #undef STEPB
            int gbase = __shfl(mybase, bin);
            nodes_b[gbase + off] = node;
        }
    }
}

// bin = bid&7 -> XCD round-robin affinity; each bin's cum slice is 2MB (L2-fit).
__global__ void k_gather(const int* __restrict__ nodes_b,
                         const float* __restrict__ cum,
                         const int* __restrict__ binStart,
                         float* __restrict__ vals_b) {
    int b = blockIdx.x & 7;
    int s = binStart[b], e = binStart[b + 1];
    int stride = (gridDim.x >> 3) * blockDim.x;
    int i = s + (blockIdx.x >> 3) * blockDim.x + threadIdx.x;
    for (; i < e; i += stride)
        vals_b[i] = cum[__builtin_nontemporal_load(nodes_b + i)];
}

__global__ void k_merge(const int* __restrict__ ptn, const int* __restrict__ bases,
                        const float* __restrict__ vals_b, float* __restrict__ out,
                        int shift) {
    int wave = blockIdx.x * (blockDim.x >> 6) + (threadIdx.x >> 6);
    int lane = threadIdx.x & 63;
    unsigned long long lt = (1ull << lane) - 1ull;
    const v4i* p4 = reinterpret_cast<const v4i*>(ptn) + (size_t)wave * 1024;
    int mybase = (lane < 8) ? bases[wave*8 + lane] : 0;
    int w0=0,w1=0,w2=0,w3=0,w4=0,w5=0,w6=0,w7=0;
    for (int t = 0; t < 16; ++t) {
        v4i ia = __builtin_nontemporal_load(p4 + t*64 + lane);
        v4f o;
        #pragma unroll
        for (int c = 0; c < 4; ++c) {
            int bin = ia[c] >> shift;
            int off = 0;
            #define STEPB(B, W) { unsigned long long m = __ballot(bin == B); \
                if (bin == B) off = W + (int)__popcll(m & lt); W += (int)__popcll(m); }
            STEPB(0,w0) STEPB(1,w1) STEPB(2,w2) STEPB(3,w3)
            STEPB(4,w4) STEPB(5,w5) STEPB(6,w6) STEPB(7,w7)
            #undef STEPB
            int gbase = __shfl(mybase, bin);
            o[c] = vals_b[gbase + off];
        }
        reinterpret_cast<v4f*>(out)[(size_t)wave * 1024 + t*64 + lane] = o;
    }
}

extern "C" void kernel_launch(void* const* d_in, const int* in_sizes, int n_in,
                              void* d_out, int out_size, void* d_ws, size_t ws_size,
                              hipStream_t stream) {
    const float* attrs   = (const float*)d_in[0];
    const float* weight  = (const float*)d_in[1];
    const float* bias    = (const float*)d_in[2];
    const float* residue = (const float*)d_in[3];
    const int*   parent  = (const int*)d_in[4];
    const int*   ptn     = (const int*)d_in[5];
    float* out = (float*)d_out;

    const int N  = in_sizes[3];
    const int HW = in_sizes[5];
    const int BLK = 256;

    auto align256 = [](size_t x) { return (x + 255) & ~(size_t)255; };
    const size_t cumB    = align256((size_t)(N + 1) * 4);
    const size_t packedB = (size_t)(N + 1) * 8;
    const size_t nodesB  = (size_t)HW * 4;
    const size_t regA    = align256(packedB > nodesB ? packedB : nodesB);
    const size_t valsB   = align256((size_t)HW * 4);
    const int nWaves = HW / 4096;
    const size_t cntB = align256((size_t)nWaves * 8 * 4);
    const size_t needBinned = cumB + regA + valsB + 2 * cntB + 256;

    float* cum    = (float*)d_ws;
    int2*  packed = (int2*)((char*)d_ws + cumB);

    // 1) gate + pack
    int g1 = (N + 1 + BLK - 1) / BLK;
    k_gate_pack<<<g1, BLK, 0, stream>>>(attrs, weight, bias, residue, parent,
                                        packed, N);

    // 2) leveled walk: cutoffs 16K / 256K / 1M / N
    int c0 = 16384;   if (c0 > N) c0 = N;
    int c1 = 262144;  if (c1 > N) c1 = N;
    int c2 = 1048576; if (c2 > N) c2 = N;

    k_walk_lvl0<<<(c0 + BLK - 1) / BLK, BLK, 0, stream>>>(packed, cum, c0, N);
    if (c1 > c0)
        k_walk_lvl<<<(c1 - c0 + BLK - 1) / BLK, BLK, 0, stream>>>(packed, cum, c0, c1, c0);
    if (c2 > c1)
        k_walk_lvl<<<(c2 - c1 + BLK - 1) / BLK, BLK, 0, stream>>>(packed, cum, c1, c2, c1);
    if (N > c2)
        k_walk_lvl<<<(N - c2 + BLK - 1) / BLK, BLK, 0, stream>>>(packed, cum, c2, N, c2);

    // 3) pixel gather
    bool binnedOK = (HW % 4096 == 0) && (nWaves % 64 == 0) && (nWaves >= 64) &&
                    (ws_size >= needBinned) && (N > 8);
    if (binnedOK) {
        int shift = 0;
        while (((long)(N - 1) >> shift) > 7) ++shift;   // 8 bins cover [0,N)

        int*   nodes_b  = (int*)((char*)d_ws + cumB);            // aliases packed (dead after walk)
        float* vals_b   = (float*)((char*)d_ws + cumB + regA);
        int*   counts   = (int*)((char*)d_ws + cumB + regA + valsB);
        int*   bases    = (int*)((char*)d_ws + cumB + regA + valsB + cntB);
        int*   binStart = (int*)((char*)d_ws + cumB + regA + valsB + 2 * cntB);

        int gWave = nWaves / 4;   // 4 waves per 256-thread block
        k_count  <<<gWave, BLK, 0, stream>>>(ptn, counts, shift);
        k_scan   <<<1, 512, 0, stream>>>(counts, bases, binStart, nWaves);
        k_scatter<<<gWave, BLK, 0, stream>>>(ptn, bases, nodes_b, shift);
        k_gather <<<2048, BLK, 0, stream>>>(nodes_b, cum, binStart, vals_b);
        k_merge  <<<gWave, BLK, 0, stream>>>(ptn, bases, vals_b, out, shift);
    } else {
        int nQuads = (HW + 3) / 4;
        k_pixel_gather<<<(nQuads + BLK - 1) / BLK, BLK, 0, stream>>>(cum, ptn, out, HW);
    }
}

// Round 7
// 364.647 us; speedup vs baseline: 1.0197x; 1.0197x over previous
//
#include <hip/hip_runtime.h>
#include <hip/hip_bf16.h>

// Connected filter:
//   vals[i] = sigmoid(clamp(100*(attrs[i]·w + b), ±12)) * residue[i]
//   cum[i]  = sum of vals along parent chain from i up to root (dummy N terminates)
//   out[p]  = cum[pixel_to_node[p]]
// parent[i] < i (topological), parent[N] = N (dummy, val 0).
//
// Pipeline:
//   1. fused gate+pack & bin-count (independent, both BW-bound -> one dispatch)
//   2. leveled walk (cutoffs 16K/256K/1M/N) -> cum
//   3. binned pixel gather: 8 bins of 2MB (per-XCD-L2-sized), deterministic
//      ballot/scan compaction, ILP-4 gather, merge back in pixel order.
// Lessons baked in:
//  - nt-* builtins need ext_vector_type. nt-STORES double WRITE_SIZE -> never.
//  - ×8-contiguous-per-thread stores leak partial-line writebacks -> one v4f
//    store per lane-dense iter (merge).
//  - R6: k_gather was latency-bound (1.08 TB/s, VALUBusy 2.5%): serial
//    load->gather->store chain, 1 outstanding/thread -> 4-way ILP this round.

typedef float v2f __attribute__((ext_vector_type(2)));
typedef float v4f __attribute__((ext_vector_type(4)));
typedef int   v4i __attribute__((ext_vector_type(4)));

// ---------------- Kernel 1: fused gate+pack | bin-count ----------------------
__global__ void k_gate_count(const float* __restrict__ attrs,
                             const float* __restrict__ w,
                             const float* __restrict__ bias,
                             const float* __restrict__ residue,
                             const int*   __restrict__ parent,
                             int2* __restrict__ packed, int N,
                             const int* __restrict__ ptn,
                             int* __restrict__ counts, int shift, int g1) {
    if ((int)blockIdx.x >= g1) {
        // ---- bin-count branch: one wave counts 4096 pixels ----
        int wave = (blockIdx.x - g1) * (blockDim.x >> 6) + (threadIdx.x >> 6);
        int lane = threadIdx.x & 63;
        const v4i* p4 = reinterpret_cast<const v4i*>(ptn) + (size_t)wave * 1024;
        int c0=0,c1=0,c2=0,c3=0,c4=0,c5=0,c6=0,c7=0;
        for (int t = 0; t < 16; ++t) {
            v4i ia = __builtin_nontemporal_load(p4 + t*64 + lane);
            #pragma unroll
            for (int c = 0; c < 4; ++c) {
                int bin = ia[c] >> shift;
                #define CNTB(B, C) { unsigned long long m = __ballot(bin == B); C += (int)__popcll(m); }
                CNTB(0,c0) CNTB(1,c1) CNTB(2,c2) CNTB(3,c3)
                CNTB(4,c4) CNTB(5,c5) CNTB(6,c6) CNTB(7,c7)
                #undef CNTB
            }
        }
        int v = 0;
        if      (lane == 0) v = c0; else if (lane == 1) v = c1;
        else if (lane == 2) v = c2; else if (lane == 3) v = c3;
        else if (lane == 4) v = c4; else if (lane == 5) v = c5;
        else if (lane == 6) v = c6; else if (lane == 7) v = c7;
        if (lane < 8) counts[wave*8 + lane] = v;
        return;
    }
    // ---- gate+pack branch ----
    int i = blockIdx.x * blockDim.x + threadIdx.x;
    if (i > N) return;
    if (i == N) { int2 p; p.x = N; p.y = __float_as_int(0.0f); packed[N] = p; return; }
    const v2f* a2 = reinterpret_cast<const v2f*>(attrs + (size_t)i * 6);
    v2f a0  = __builtin_nontemporal_load(a2 + 0);
    v2f a1  = __builtin_nontemporal_load(a2 + 1);
    v2f a2v = __builtin_nontemporal_load(a2 + 2);
    float logit = bias[0]
                + a0.x  * w[0] + a0.y  * w[1]
                + a1.x  * w[2] + a1.y  * w[3]
                + a2v.x * w[4] + a2v.y * w[5];
    float s = fminf(fmaxf(100.0f * logit, -12.0f), 12.0f);
    float gate = 1.0f / (1.0f + __expf(-s));
    float vv = gate * __builtin_nontemporal_load(residue + i);
    int2 p; p.x = __builtin_nontemporal_load(parent + i); p.y = __float_as_int(vv);
    packed[i] = p;
}

// ---------------- Kernel 2: leveled walk --------------------------------------
__global__ void k_walk_lvl0(const int2* __restrict__ packed,
                            float* __restrict__ cum, int hi, int N) {
    int i = blockIdx.x * blockDim.x + threadIdx.x;
    if (i >= hi) return;
    float s = 0.0f; int j = i;
    while (j != N) { int2 pv = packed[j]; s += __int_as_float(pv.y); j = pv.x; }
    cum[i] = s;
}

__global__ void k_walk_lvl(const int2* __restrict__ packed,
                           float* __restrict__ cum, int lo, int hi, int cutoff) {
    int i = lo + blockIdx.x * blockDim.x + threadIdx.x;
    if (i >= hi) return;
    float s = 0.0f; int j = i;
    do { int2 pv = packed[j]; s += __int_as_float(pv.y); j = pv.x; } while (j >= cutoff);
    cum[i] = s + cum[j];
}

// ---------------- Fallback: direct pixel gather -------------------------------
__global__ void k_pixel_gather(const float* __restrict__ cum,
                               const int* __restrict__ ptn,
                               float* __restrict__ out, int M) {
    int t = blockIdx.x * blockDim.x + threadIdx.x;
    int base = t * 4;
    if (base + 3 < M) {
        v4i idx = __builtin_nontemporal_load(reinterpret_cast<const v4i*>(ptn) + t);
        float4 o;
        o.x = cum[idx.x]; o.y = cum[idx.y]; o.z = cum[idx.z]; o.w = cum[idx.w];
        reinterpret_cast<float4*>(out)[t] = o;
    } else {
        for (int p = base; p < M; ++p) out[p] = cum[ptn[p]];
    }
}

// ---------------- Binned gather pipeline --------------------------------------
// 1 block, 512 threads = 8 bins x 64 lanes. Deterministic scan.
__global__ void k_scan(const int* __restrict__ counts, int* __restrict__ bases,
                       int* __restrict__ binStart, int nWaves) {
    int b = threadIdx.x >> 6;
    int lane = threadIdx.x & 63;
    int g = nWaves >> 6;
    int w0 = lane * g;
    int sum = 0;
    for (int w = w0; w < w0 + g; ++w) sum += counts[w*8 + b];
    int inc = sum;
    #pragma unroll
    for (int d = 1; d < 64; d <<= 1) {
        int o = __shfl_up(inc, d);
        if (lane >= d) inc += o;
    }
    int excl = inc - sum;
    __shared__ int totals[8];
    __shared__ int bstart[9];
    if (lane == 63) totals[b] = inc;
    __syncthreads();
    if (threadIdx.x == 0) {
        bstart[0] = 0;
        for (int i = 0; i < 8; ++i) bstart[i+1] = bstart[i] + totals[i];
        for (int i = 0; i < 9; ++i) binStart[i] = bstart[i];
    }
    __syncthreads();
    int run = bstart[b] + excl;
    for (int w = w0; w < w0 + g; ++w) { bases[w*8 + b] = run; run += counts[w*8 + b]; }
}

__global__ void k_scatter(const int* __restrict__ ptn, const int* __restrict__ bases,
                          int* __restrict__ nodes_b, int shift) {
    int wave = blockIdx.x * (blockDim.x >> 6) + (threadIdx.x >> 6);
    int lane = threadIdx.x & 63;
    unsigned long long lt = (1ull << lane) - 1ull;
    const v4i* p4 = reinterpret_cast<const v4i*>(ptn) + (size_t)wave * 1024;
    int mybase = (lane < 8) ? bases[wave*8 + lane] : 0;
    int w0=0,w1=0,w2=0,w3=0,w4=0,w5=0,w6=0,w7=0;
    for (int t = 0; t < 16; ++t) {
        v4i ia = __builtin_nontemporal_load(p4 + t*64 + lane);
        #pragma unroll
        for (int c = 0; c < 4; ++c) {
            int node = ia[c];
            int bin = node >> shift;
            int off = 0;
            #define STEPB(B, W) { unsigned long long m = __ballot(bin == B); \
                if (bin == B) off = W + (int)__popcll(m & lt); W += (int)__popcll(m); }
            STEPB(0,w0) STEPB(1,w1) STEPB(2,w2) STEPB(3,w3)
            STEPB(4,w4) STEPB(5,w5) STEPB(6,w6) STEPB(7,w7)
            #undef STEPB
            int gbase = __shfl(mybase, bin);
            nodes_b[gbase + off] = node;
        }
    }
}

// bin = bid&7 -> XCD round-robin affinity; each bin's cum slice is 2MB (L2-fit).
// ILP-4: four independent load->gather->store chains per thread per iteration.
__global__ void k_gather(const int* __restrict__ nodes_b,
                         const float* __restrict__ cum,
                         const int* __restrict__ binStart,
                         float* __restrict__ vals_b) {
    int b = blockIdx.x & 7;
    int s = binStart[b], e = binStart[b + 1];
    int T = (gridDim.x >> 3) * blockDim.x;
    int i = s + (blockIdx.x >> 3) * blockDim.x + threadIdx.x;
    while (i + 3 * T < e) {
        int n0 = __builtin_nontemporal_load(nodes_b + i);
        int n1 = __builtin_nontemporal_load(nodes_b + i + T);
        int n2 = __builtin_nontemporal_load(nodes_b + i + 2 * T);
        int n3 = __builtin_nontemporal_load(nodes_b + i + 3 * T);
        float v0 = cum[n0], v1 = cum[n1], v2 = cum[n2], v3 = cum[n3];
        vals_b[i]         = v0;
        vals_b[i + T]     = v1;
        vals_b[i + 2 * T] = v2;
        vals_b[i + 3 * T] = v3;
        i += 4 * T;
    }
    for (; i < e; i += T)
        vals_b[i] = cum[__builtin_nontemporal_load(nodes_b + i)];
}

__global__ void k_merge(const int* __restrict__ ptn, const int* __restrict__ bases,
                        const float* __restrict__ vals_b, float* __restrict__ out,
                        int shift) {
    int wave = blockIdx.x * (blockDim.x >> 6) + (threadIdx.x >> 6);
    int lane = threadIdx.x & 63;
    unsigned long long lt = (1ull << lane) - 1ull;
    const v4i* p4 = reinterpret_cast<const v4i*>(ptn) + (size_t)wave * 1024;
    int mybase = (lane < 8) ? bases[wave*8 + lane] : 0;
    int w0=0,w1=0,w2=0,w3=0,w4=0,w5=0,w6=0,w7=0;
    for (int t = 0; t < 16; ++t) {
        v4i ia = __builtin_nontemporal_load(p4 + t*64 + lane);
        v4f o;
        #pragma unroll
        for (int c = 0; c < 4; ++c) {
            int bin = ia[c] >> shift;
            int off = 0;
            #define STEPB(B, W) { unsigned long long m = __ballot(bin == B); \
                if (bin == B) off = W + (int)__popcll(m & lt); W += (int)__popcll(m); }
            STEPB(0,w0) STEPB(1,w1) STEPB(2,w2) STEPB(3,w3)
            STEPB(4,w4) STEPB(5,w5) STEPB(6,w6) STEPB(7,w7)
            #undef STEPB
            int gbase = __shfl(mybase, bin);
            o[c] = vals_b[gbase + off];
        }
        reinterpret_cast<v4f*>(out)[(size_t)wave * 1024 + t*64 + lane] = o;
    }
}

extern "C" void kernel_launch(void* const* d_in, const int* in_sizes, int n_in,
                              void* d_out, int out_size, void* d_ws, size_t ws_size,
                              hipStream_t stream) {
    const float* attrs   = (const float*)d_in[0];
    const float* weight  = (const float*)d_in[1];
    const float* bias    = (const float*)d_in[2];
    const float* residue = (const float*)d_in[3];
    const int*   parent  = (const int*)d_in[4];
    const int*   ptn     = (const int*)d_in[5];
    float* out = (float*)d_out;

    const int N  = in_sizes[3];
    const int HW = in_sizes[5];
    const int BLK = 256;

    auto align256 = [](size_t x) { return (x + 255) & ~(size_t)255; };
    const size_t cumB    = align256((size_t)(N + 1) * 4);
    const size_t packedB = (size_t)(N + 1) * 8;
    const size_t nodesB  = (size_t)HW * 4;
    const size_t regA    = align256(packedB > nodesB ? packedB : nodesB);
    const size_t valsB   = align256((size_t)HW * 4);
    const int nWaves = HW / 4096;
    const size_t cntB = align256((size_t)nWaves * 8 * 4);
    const size_t needBinned = cumB + regA + valsB + 2 * cntB + 256;

    float* cum    = (float*)d_ws;
    int2*  packed = (int2*)((char*)d_ws + cumB);

    bool binnedOK = (HW % 4096 == 0) && (nWaves % 64 == 0) && (nWaves >= 64) &&
                    (ws_size >= needBinned) && (N > 8);

    int shift = 0;
    while (((long)(N - 1) >> shift) > 7) ++shift;   // 8 bins cover [0,N)

    int*   nodes_b  = (int*)((char*)d_ws + cumB);   // aliases packed (dead after walk)
    float* vals_b   = (float*)((char*)d_ws + cumB + regA);
    int*   counts   = (int*)((char*)d_ws + cumB + regA + valsB);
    int*   bases    = (int*)((char*)d_ws + cumB + regA + valsB + cntB);
    int*   binStart = (int*)((char*)d_ws + cumB + regA + valsB + 2 * cntB);

    // 1) fused gate+pack | count
    int g1 = (N + 1 + BLK - 1) / BLK;
    int gWave = binnedOK ? (nWaves / 4) : 0;   // 4 waves per 256-thread block
    k_gate_count<<<g1 + gWave, BLK, 0, stream>>>(attrs, weight, bias, residue,
                                                 parent, packed, N,
                                                 ptn, counts, shift, g1);

    // 2) leveled walk: cutoffs 16K / 256K / 1M / N
    int c0 = 16384;   if (c0 > N) c0 = N;
    int c1 = 262144;  if (c1 > N) c1 = N;
    int c2 = 1048576; if (c2 > N) c2 = N;

    k_walk_lvl0<<<(c0 + BLK - 1) / BLK, BLK, 0, stream>>>(packed, cum, c0, N);
    if (c1 > c0)
        k_walk_lvl<<<(c1 - c0 + BLK - 1) / BLK, BLK, 0, stream>>>(packed, cum, c0, c1, c0);
    if (c2 > c1)
        k_walk_lvl<<<(c2 - c1 + BLK - 1) / BLK, BLK, 0, stream>>>(packed, cum, c1, c2, c1);
    if (N > c2)
        k_walk_lvl<<<(N - c2 + BLK - 1) / BLK, BLK, 0, stream>>>(packed, cum, c2, N, c2);

    // 3) pixel gather
    if (binnedOK) {
        k_scan   <<<1, 512, 0, stream>>>(counts, bases, binStart, nWaves);
        k_scatter<<<nWaves / 4, BLK, 0, stream>>>(ptn, bases, nodes_b, shift);
        k_gather <<<2048, BLK, 0, stream>>>(nodes_b, cum, binStart, vals_b);
        k_merge  <<<nWaves / 4, BLK, 0, stream>>>(ptn, bases, vals_b, out, shift);
    } else {
        int nQuads = (HW + 3) / 4;
        k_pixel_gather<<<(nQuads + BLK - 1) / BLK, BLK, 0, stream>>>(cum, ptn, out, HW);
    }
}

// Round 8
// 337.687 us; speedup vs baseline: 1.1011x; 1.0798x over previous
//
#include <hip/hip_runtime.h>
#include <hip/hip_bf16.h>

// Connected filter:
//   vals[i] = sigmoid(clamp(100*(attrs[i]·w + b), ±12)) * residue[i]
//   cum[i]  = sum of vals along parent chain from i up to root (dummy N terminates)
//   out[p]  = cum[pixel_to_node[p]]
// parent[i] < i (topological), parent[N] = N (dummy, val 0).
//
// Pipeline (7 dispatches):
//   1. gate+pack | bin-count            (fused, independent streams)
//   2. walk L0 | scan                   (fused; scan = 1 block, 64-aligned bins)
//   3. walk L1   4. walk L2
//   5. walk L3 | scatter                (fused; scatter blocks first)
//   6. gather (ILP-8, in-place nv: index -> value)
//   7. merge (ballot-recomputed offsets, v4f lane-dense out)
// Lessons baked in:
//  - nt-* builtins need ext_vector_type. nt-STORES double WRITE_SIZE -> never.
//  - >4 contiguous floats per thread leak partial-line writebacks -> x4 lane-dense.
//  - R7: gather ILP-4 only 112->103us @1.18TB/s: suspect L2 random-request wall
//    (~8/cy/XCD). This round: ILP-8 A/B. nodes/vals share one buffer in-place
//    so scatter can run concurrently with walk L3 (packed stays live).

typedef float v2f __attribute__((ext_vector_type(2)));
typedef float v4f __attribute__((ext_vector_type(4)));
typedef int   v4i __attribute__((ext_vector_type(4)));

// ---------------- Kernel 1: fused gate+pack | bin-count ----------------------
__global__ void k_gate_count(const float* __restrict__ attrs,
                             const float* __restrict__ w,
                             const float* __restrict__ bias,
                             const float* __restrict__ residue,
                             const int*   __restrict__ parent,
                             int2* __restrict__ packed, int N,
                             const int* __restrict__ ptn,
                             int* __restrict__ counts, int shift, int g1) {
    if ((int)blockIdx.x >= g1) {
        int wave = (blockIdx.x - g1) * (blockDim.x >> 6) + (threadIdx.x >> 6);
        int lane = threadIdx.x & 63;
        const v4i* p4 = reinterpret_cast<const v4i*>(ptn) + (size_t)wave * 1024;
        int c0=0,c1=0,c2=0,c3=0,c4=0,c5=0,c6=0,c7=0;
        for (int t = 0; t < 16; ++t) {
            v4i ia = __builtin_nontemporal_load(p4 + t*64 + lane);
            #pragma unroll
            for (int c = 0; c < 4; ++c) {
                int bin = ia[c] >> shift;
                #define CNTB(B, C) { unsigned long long m = __ballot(bin == B); C += (int)__popcll(m); }
                CNTB(0,c0) CNTB(1,c1) CNTB(2,c2) CNTB(3,c3)
                CNTB(4,c4) CNTB(5,c5) CNTB(6,c6) CNTB(7,c7)
                #undef CNTB
            }
        }
        int v = 0;
        if      (lane == 0) v = c0; else if (lane == 1) v = c1;
        else if (lane == 2) v = c2; else if (lane == 3) v = c3;
        else if (lane == 4) v = c4; else if (lane == 5) v = c5;
        else if (lane == 6) v = c6; else if (lane == 7) v = c7;
        if (lane < 8) counts[wave*8 + lane] = v;
        return;
    }
    int i = blockIdx.x * blockDim.x + threadIdx.x;
    if (i > N) return;
    if (i == N) { int2 p; p.x = N; p.y = __float_as_int(0.0f); packed[N] = p; return; }
    const v2f* a2 = reinterpret_cast<const v2f*>(attrs + (size_t)i * 6);
    v2f a0  = __builtin_nontemporal_load(a2 + 0);
    v2f a1  = __builtin_nontemporal_load(a2 + 1);
    v2f a2v = __builtin_nontemporal_load(a2 + 2);
    float logit = bias[0]
                + a0.x  * w[0] + a0.y  * w[1]
                + a1.x  * w[2] + a1.y  * w[3]
                + a2v.x * w[4] + a2v.y * w[5];
    float s = fminf(fmaxf(100.0f * logit, -12.0f), 12.0f);
    float gate = 1.0f / (1.0f + __expf(-s));
    float vv = gate * __builtin_nontemporal_load(residue + i);
    int2 p; p.x = __builtin_nontemporal_load(parent + i); p.y = __float_as_int(vv);
    packed[i] = p;
}

// ---------------- scan body (256 threads, 1 block): 64-padded bin starts -----
__device__ void scan_body(const int* __restrict__ counts, int* __restrict__ bases,
                          int* __restrict__ binStart, int* __restrict__ binCnt,
                          int nWaves) {
    int tid = threadIdx.x;
    int b = tid >> 5;            // 8 bins x 32 lanes
    int l = tid & 31;
    int g = nWaves >> 5;
    int w0 = l * g;
    int sum = 0;
    for (int w = w0; w < w0 + g; ++w) sum += counts[w*8 + b];
    int inc = sum;
    #pragma unroll
    for (int d = 1; d < 32; d <<= 1) {
        int o = __shfl_up(inc, d);   // wave64: lanes 32..63 = second bin; guard by l
        if (l >= d) inc += o;
    }
    int excl = inc - sum;
    __shared__ int totals[8];
    __shared__ int bstart[9];
    if (l == 31) totals[b] = inc;
    __syncthreads();
    if (tid == 0) {
        bstart[0] = 0;
        for (int i = 0; i < 8; ++i) {
            binCnt[i] = totals[i];
            bstart[i+1] = bstart[i] + ((totals[i] + 63) & ~63);   // 64-align starts
        }
        for (int i = 0; i < 9; ++i) binStart[i] = bstart[i];
    }
    __syncthreads();
    int run = bstart[b] + excl;
    for (int w = w0; w < w0 + g; ++w) { bases[w*8 + b] = run; run += counts[w*8 + b]; }
}

// ---------------- Kernel 2: fused walk L0 | scan ------------------------------
__global__ void k_walk0_scan(const int2* __restrict__ packed,
                             float* __restrict__ cum, int hi, int N,
                             const int* __restrict__ counts, int* __restrict__ bases,
                             int* __restrict__ binStart, int* __restrict__ binCnt,
                             int nWaves) {
    if (blockIdx.x == 0) { scan_body(counts, bases, binStart, binCnt, nWaves); return; }
    int i = (blockIdx.x - 1) * blockDim.x + threadIdx.x;
    if (i >= hi) return;
    float s = 0.0f; int j = i;
    while (j != N) { int2 pv = packed[j]; s += __int_as_float(pv.y); j = pv.x; }
    cum[i] = s;
}

__global__ void k_walk_lvl0(const int2* __restrict__ packed,
                            float* __restrict__ cum, int hi, int N) {
    int i = blockIdx.x * blockDim.x + threadIdx.x;
    if (i >= hi) return;
    float s = 0.0f; int j = i;
    while (j != N) { int2 pv = packed[j]; s += __int_as_float(pv.y); j = pv.x; }
    cum[i] = s;
}

__global__ void k_walk_lvl(const int2* __restrict__ packed,
                           float* __restrict__ cum, int lo, int hi, int cutoff) {
    int i = lo + blockIdx.x * blockDim.x + threadIdx.x;
    if (i >= hi) return;
    float s = 0.0f; int j = i;
    do { int2 pv = packed[j]; s += __int_as_float(pv.y); j = pv.x; } while (j >= cutoff);
    cum[i] = s + cum[j];
}

// ---------------- Kernel 5: fused scatter | walk L3 ---------------------------
// scatter blocks FIRST (long-running, start early); walk fills in behind.
__global__ void k_scatter_walk3(const int* __restrict__ ptn,
                                const int* __restrict__ bases,
                                int* __restrict__ nodes_b, int shift, int gS,
                                const int2* __restrict__ packed,
                                float* __restrict__ cum, int lo, int hi, int cutoff) {
    if ((int)blockIdx.x < gS) {
        int wave = blockIdx.x * (blockDim.x >> 6) + (threadIdx.x >> 6);
        int lane = threadIdx.x & 63;
        unsigned long long lt = (1ull << lane) - 1ull;
        const v4i* p4 = reinterpret_cast<const v4i*>(ptn) + (size_t)wave * 1024;
        int mybase = (lane < 8) ? bases[wave*8 + lane] : 0;
        int w0=0,w1=0,w2=0,w3=0,w4=0,w5=0,w6=0,w7=0;
        for (int t = 0; t < 16; ++t) {
            v4i ia = __builtin_nontemporal_load(p4 + t*64 + lane);
            #pragma unroll
            for (int c = 0; c < 4; ++c) {
                int node = ia[c];
                int bin = node >> shift;
                int off = 0;
                #define STEPB(B, W) { unsigned long long m = __ballot(bin == B); \
                    if (bin == B) off = W + (int)__popcll(m & lt); W += (int)__popcll(m); }
                STEPB(0,w0) STEPB(1,w1) STEPB(2,w2) STEPB(3,w3)
                STEPB(4,w4) STEPB(5,w5) STEPB(6,w6) STEPB(7,w7)
                #undef STEPB
                int gbase = __shfl(mybase, bin);
                nodes_b[gbase + off] = node;
            }
        }
        return;
    }
    int i = lo + (blockIdx.x - gS) * blockDim.x + threadIdx.x;
    if (i >= hi) return;
    float s = 0.0f; int j = i;
    do { int2 pv = packed[j]; s += __int_as_float(pv.y); j = pv.x; } while (j >= cutoff);
    cum[i] = s + cum[j];
}

// ---------------- Kernel 6: gather, ILP-8, in-place (index -> value) ----------
__global__ __launch_bounds__(256) void k_gather(int* __restrict__ nv,
                                                const float* __restrict__ cum,
                                                const int* __restrict__ binStart,
                                                const int* __restrict__ binCnt) {
    int b = blockIdx.x & 7;
    int s = binStart[b];                 // multiple of 64 -> v4i aligned
    int cnt = binCnt[b];
    int nq = cnt >> 2;
    int T = (gridDim.x >> 3) * blockDim.x;
    int q0 = (blockIdx.x >> 3) * blockDim.x + threadIdx.x;
    v4i* np = reinterpret_cast<v4i*>(nv + s);
    int q = q0;
    for (; q + T < nq; q += 2 * T) {
        v4i na = __builtin_nontemporal_load(np + q);
        v4i nb = __builtin_nontemporal_load(np + q + T);
        v4f va, vb;                      // 8 independent gathers in flight
        va.x = cum[na.x]; va.y = cum[na.y]; va.z = cum[na.z]; va.w = cum[na.w];
        vb.x = cum[nb.x]; vb.y = cum[nb.y]; vb.z = cum[nb.z]; vb.w = cum[nb.w];
        reinterpret_cast<v4f*>(np)[q]     = va;   // in-place: same thread, same slot
        reinterpret_cast<v4f*>(np)[q + T] = vb;
    }
    for (; q < nq; q += T) {
        v4i na = __builtin_nontemporal_load(np + q);
        v4f va;
        va.x = cum[na.x]; va.y = cum[na.y]; va.z = cum[na.z]; va.w = cum[na.w];
        reinterpret_cast<v4f*>(np)[q] = va;
    }
    if (q0 < (cnt & 3)) {
        int i = s + nq * 4 + q0;
        float v = cum[nv[i]];
        reinterpret_cast<float*>(nv)[i] = v;
    }
}

// ---------------- Kernel 7: merge back in pixel order -------------------------
__global__ void k_merge(const int* __restrict__ ptn, const int* __restrict__ bases,
                        const float* __restrict__ vals_b, float* __restrict__ out,
                        int shift) {
    int wave = blockIdx.x * (blockDim.x >> 6) + (threadIdx.x >> 6);
    int lane = threadIdx.x & 63;
    unsigned long long lt = (1ull << lane) - 1ull;
    const v4i* p4 = reinterpret_cast<const v4i*>(ptn) + (size_t)wave * 1024;
    int mybase = (lane < 8) ? bases[wave*8 + lane] : 0;
    int w0=0,w1=0,w2=0,w3=0,w4=0,w5=0,w6=0,w7=0;
    for (int t = 0; t < 16; ++t) {
        v4i ia = __builtin_nontemporal_load(p4 + t*64 + lane);
        v4f o;
        #pragma unroll
        for (int c = 0; c < 4; ++c) {
            int bin = ia[c] >> shift;
            int off = 0;
            #define STEPB(B, W) { unsigned long long m = __ballot(bin == B); \
                if (bin == B) off = W + (int)__popcll(m & lt); W += (int)__popcll(m); }
            STEPB(0,w0) STEPB(1,w1) STEPB(2,w2) STEPB(3,w3)
            STEPB(4,w4) STEPB(5,w5) STEPB(6,w6) STEPB(7,w7)
            #undef STEPB
            int gbase = __shfl(mybase, bin);
            o[c] = vals_b[gbase + off];
        }
        reinterpret_cast<v4f*>(out)[(size_t)wave * 1024 + t*64 + lane] = o;
    }
}

// ---------------- Fallback: direct pixel gather -------------------------------
__global__ void k_pixel_gather(const float* __restrict__ cum,
                               const int* __restrict__ ptn,
                               float* __restrict__ out, int M) {
    int t = blockIdx.x * blockDim.x + threadIdx.x;
    int base = t * 4;
    if (base + 3 < M) {
        v4i idx = __builtin_nontemporal_load(reinterpret_cast<const v4i*>(ptn) + t);
        float4 o;
        o.x = cum[idx.x]; o.y = cum[idx.y]; o.z = cum[idx.z]; o.w = cum[idx.w];
        reinterpret_cast<float4*>(out)[t] = o;
    } else {
        for (int p = base; p < M; ++p) out[p] = cum[ptn[p]];
    }
}

extern "C" void kernel_launch(void* const* d_in, const int* in_sizes, int n_in,
                              void* d_out, int out_size, void* d_ws, size_t ws_size,
                              hipStream_t stream) {
    const float* attrs   = (const float*)d_in[0];
    const float* weight  = (const float*)d_in[1];
    const float* bias    = (const float*)d_in[2];
    const float* residue = (const float*)d_in[3];
    const int*   parent  = (const int*)d_in[4];
    const int*   ptn     = (const int*)d_in[5];
    float* out = (float*)d_out;

    const int N  = in_sizes[3];
    const int HW = in_sizes[5];
    const int BLK = 256;

    auto align256 = [](size_t x) { return (x + 255) & ~(size_t)255; };
    const size_t cumB    = align256((size_t)(N + 1) * 4);
    const size_t packedB = align256((size_t)(N + 1) * 8);
    const size_t nvB     = align256(((size_t)HW + 512) * 4);   // nodes/vals in-place
    const int nWaves = HW / 4096;
    const size_t cntB = align256((size_t)nWaves * 8 * 4);
    const size_t needBinned = cumB + packedB + nvB + 2 * cntB + 256;

    float* cum    = (float*)d_ws;
    int2*  packed = (int2*)((char*)d_ws + cumB);
    int*   nv     = (int*)((char*)d_ws + cumB + packedB);
    int*   counts = (int*)((char*)d_ws + cumB + packedB + nvB);
    int*   bases  = (int*)((char*)d_ws + cumB + packedB + nvB + cntB);
    int*   binStart = (int*)((char*)d_ws + cumB + packedB + nvB + 2 * cntB);
    int*   binCnt   = binStart + 16;

    bool binnedOK = (HW % 4096 == 0) && (nWaves % 64 == 0) && (nWaves >= 64) &&
                    (ws_size >= needBinned) && (N > 8);

    int shift = 0;
    while (((long)(N - 1) >> shift) > 7) ++shift;   // 8 bins cover [0,N)

    // 1) fused gate+pack | count
    int g1 = (N + 1 + BLK - 1) / BLK;
    int gWave = binnedOK ? (nWaves / 4) : 0;
    k_gate_count<<<g1 + gWave, BLK, 0, stream>>>(attrs, weight, bias, residue,
                                                 parent, packed, N,
                                                 ptn, counts, shift, g1);

    // walk cutoffs 16K / 256K / 1M / N
    int c0 = 16384;   if (c0 > N) c0 = N;
    int c1 = 262144;  if (c1 > N) c1 = N;
    int c2 = 1048576; if (c2 > N) c2 = N;

    if (binnedOK) {
        // 2) walk L0 | scan
        int g20 = (c0 + BLK - 1) / BLK;
        k_walk0_scan<<<g20 + 1, BLK, 0, stream>>>(packed, cum, c0, N,
                                                  counts, bases, binStart, binCnt,
                                                  nWaves);
        // 3,4) walk L1, L2
        if (c1 > c0)
            k_walk_lvl<<<(c1 - c0 + BLK - 1) / BLK, BLK, 0, stream>>>(packed, cum, c0, c1, c0);
        if (c2 > c1)
            k_walk_lvl<<<(c2 - c1 + BLK - 1) / BLK, BLK, 0, stream>>>(packed, cum, c1, c2, c1);
        // 5) scatter | walk L3
        int gS = nWaves / 4;
        int gW3 = (N > c2) ? (N - c2 + BLK - 1) / BLK : 0;
        k_scatter_walk3<<<gS + gW3, BLK, 0, stream>>>(ptn, bases, nv, shift, gS,
                                                      packed, cum, c2, N, c2);
        // 6) gather (in-place), 7) merge
        k_gather<<<2048, BLK, 0, stream>>>(nv, cum, binStart, binCnt);
        k_merge <<<nWaves / 4, BLK, 0, stream>>>(ptn, bases, (const float*)nv, out, shift);
    } else {
        k_walk_lvl0<<<(c0 + BLK - 1) / BLK, BLK, 0, stream>>>(packed, cum, c0, N);
        if (c1 > c0)
            k_walk_lvl<<<(c1 - c0 + BLK - 1) / BLK, BLK, 0, stream>>>(packed, cum, c0, c1, c0);
        if (c2 > c1)
            k_walk_lvl<<<(c2 - c1 + BLK - 1) / BLK, BLK, 0, stream>>>(packed, cum, c1, c2, c1);
        if (N > c2)
            k_walk_lvl<<<(N - c2 + BLK - 1) / BLK, BLK, 0, stream>>>(packed, cum, c2, N, c2);
        int nQuads = (HW + 3) / 4;
        k_pixel_gather<<<(nQuads + BLK - 1) / BLK, BLK, 0, stream>>>(cum, ptn, out, HW);
    }
}